// Round 12
// baseline (21676.358 us; speedup 1.0000x reference)
//
#include <hip/hip_runtime.h>
#include <hip/hip_bf16.h>
#include <hip/hip_fp16.h>
#include <stdint.h>

typedef _Float16 h2_t  __attribute__((ext_vector_type(2)));
typedef _Float16 f16x8 __attribute__((ext_vector_type(8)));
typedef float    f32x4 __attribute__((ext_vector_type(4)));

#define TSEQ 4096
#define HID  256
#define IN2  512
#define NB   64
#define CH   256
#define NCH  16

__device__ __forceinline__ h2_t bc_h2(uint32_t v){ return __builtin_bit_cast(h2_t, v); }

__device__ __forceinline__ float sigm_(float x){
    return __builtin_amdgcn_rcpf(1.f + __expf(-x));
}
__device__ __forceinline__ float tanh_(float x){
    return 1.f - 2.f*__builtin_amdgcn_rcpf(1.f + __expf(2.f*x));
}
__device__ __forceinline__ void sync_lds(){
    asm volatile("s_waitcnt lgkmcnt(0)\n\ts_barrier" ::: "memory");
}
__device__ __forceinline__ f32x4 mfma16(f16x8 a, f16x8 b, f32x4 c){
    return __builtin_amdgcn_mfma_f32_16x16x32_f16(a, b, c, 0, 0, 0);
}
// extract f16 element i (compile-time const) from a uint4 of 8 packed f16
__device__ __forceinline__ float f16x(uint4 v, int i){
    int wsel = i >> 1;
    uint32_t word = (wsel==0) ? v.x : (wsel==1) ? v.y : (wsel==2) ? v.z : v.w;
    h2_t hh = bc_h2(word);
    return (float)hh[i & 1];
}

// ---------------- prep --------------------------------------------------------------------
// wfrag: B-fragments for rec MFMA. Decode idx -> (L, w, t, kt, lane, j):
//   g=t>>2 (0=r,1=z,2=h~), sub=t&3; col = w*64 + sub*16 + (lane&15);
//   k = kt*32 + (lane>>4)*8 + j;  val = Wg[L][(256+k)*256 + col]  (h-part rows)
__global__ void prep_kernel(const float* __restrict__ Wr, const float* __restrict__ Wz,
                            const float* __restrict__ Wh, const float* __restrict__ emb,
                            const float* __restrict__ br, const float* __restrict__ bz,
                            const float* __restrict__ bh,
                            __half* __restrict__ wfrag, __half* __restrict__ wxt,
                            __half* __restrict__ embf16, float* __restrict__ biasv)
{
    const long long S0 = 393216LL;           // wfrag f16 count: 2*4*12*8*64*8
    const long long S1 = 2LL*768*256;        // wxt
    const long long S2 = 32000LL*256;        // emb f16
    const long long S3 = 2LL*768;            // biasv
    for (long long idx = (long long)blockIdx.x*256 + threadIdx.x; idx < S0+S1+S2+S3;
         idx += (long long)gridDim.x*256) {
        if (idx < S0) {
            int i    = (int)idx;
            int j    = i & 7;
            int lane = (i >> 3) & 63;
            int kt   = (i >> 9) & 7;
            int rest = i >> 12;              // 0..95
            int t    = rest % 12;
            int w    = (rest / 12) & 3;
            int L    = rest / 48;
            int g = t >> 2, sub = t & 3;
            int col = w*64 + sub*16 + (lane & 15);
            int k   = kt*32 + (lane >> 4)*8 + j;
            const float* Wsrc = (g==0?Wr:(g==1?Wz:Wh)) + (size_t)L*IN2*HID;
            wfrag[idx] = __float2half(Wsrc[(size_t)(256 + k)*HID + col]);
        } else if (idx < S0+S1) {
            int i  = (int)(idx - S0);
            int k  = i & 255;
            int i2 = i >> 8;
            int o  = i2 % 768, L = i2 / 768;
            int g  = o >> 8,   n = o & 255;
            const float* Wsrc = (g==0?Wr:(g==1?Wz:Wh)) + (size_t)L*IN2*HID;
            wxt[i] = __float2half(Wsrc[(size_t)k*HID + n]);
        } else if (idx < S0+S1+S2) {
            int i = (int)(idx - S0 - S1);
            embf16[i] = __float2half(emb[i]);
        } else {
            int i = (int)(idx - S0 - S1 - S2);
            int o = i % 768, L = i / 768;
            int g = o >> 8,  n = o & 255;
            const float* bsrc = (g==0?br:(g==1?bz:bh));
            biasv[i] = bsrc[L*HID + n];
        }
    }
}

// ---------------- x-projection GEMM -------------------------------------------------------
// proj layout: f16 index = (((group*CH+tl)*4 + wave)*64 + lane)*48 + (g*4+sub)*4 + q
//   group=b>>4, s=b&15, wave=(col&255)>>6, sub=(col>>4)&3, g=col>>8,
//   lane=((s>>2)<<4)|(col&15), q=s&3.   (48 f16 = 96 B per lane per step)
__global__ __launch_bounds__(256) void gemm_proj(
    const int* __restrict__ tokens, const __half* __restrict__ embf16,
    const __half* __restrict__ h0chunk, const __half* __restrict__ wxt,
    const float* __restrict__ biasv,
    __half* __restrict__ proj0, __half* __restrict__ proj1, int c0, int c1)
{
    const int Lz = blockIdx.z;
    const int c  = Lz ? c1 : c0;
    if (c < 0 || c >= NCH) return;
    __half* proj = Lz ? proj1 : proj0;

    __shared__ uint4 Ald[128*17];
    __shared__ uint4 Bld[64*17];
    const int tid = threadIdx.x;
    const int mt = blockIdx.x, nt = blockIdx.y;
    const int w = tid >> 6, l = tid & 63, lr = l & 15, lk = l >> 4;
    f32x4 acc[2][4] = {};

#pragma unroll 1
    for (int kh = 0; kh < 2; ++kh) {
        if (kh) __syncthreads();
#pragma unroll
        for (int it = 0; it < 8; ++it) {
            int idx = it*256 + tid;
            int row = idx >> 4, u4 = idx & 15;
            int grow = mt*128 + row;
            const __half* src;
            if (Lz == 0) {
                int b = grow >> 8, tl = grow & (CH-1);
                int tok = tokens[(size_t)b*TSEQ + c*CH + tl];
                src = embf16 + (size_t)tok*HID;
            } else {
                src = h0chunk + (size_t)grow*HID;
            }
            Ald[row*17 + u4] = ((const uint4*)(src + kh*128))[u4];
        }
#pragma unroll
        for (int it = 0; it < 4; ++it) {
            int idx = it*256 + tid;
            int col = idx >> 4, u4 = idx & 15;
            const __half* src = wxt + ((size_t)(Lz*768 + nt*64 + col))*HID + kh*128;
            Bld[col*17 + u4] = ((const uint4*)src)[u4];
        }
        __syncthreads();
        const _Float16* A = (const _Float16*)Ald;
        const _Float16* B = (const _Float16*)Bld;
#pragma unroll
        for (int kb = 0; kb < 4; ++kb) {
            int k0 = kb*32;
            f16x8 af[2], bf[4];
#pragma unroll
            for (int fm = 0; fm < 2; ++fm) {
                int row = w*32 + fm*16 + lr;
                af[fm] = *(const f16x8*)(A + row*136 + k0 + lk*8);
            }
#pragma unroll
            for (int fn = 0; fn < 4; ++fn) {
                int col = fn*16 + lr;
                bf[fn] = *(const f16x8*)(B + col*136 + k0 + lk*8);
            }
#pragma unroll
            for (int fm = 0; fm < 2; ++fm)
#pragma unroll
                for (int fn = 0; fn < 4; ++fn)
                    acc[fm][fn] = mfma16(af[fm], bf[fn], acc[fm][fn]);
        }
    }
#pragma unroll
    for (int fm = 0; fm < 2; ++fm)
#pragma unroll
        for (int fn = 0; fn < 4; ++fn)
#pragma unroll
            for (int q = 0; q < 4; ++q) {
                int row = mt*128 + w*32 + fm*16 + lk*4 + q;
                int col = nt*64 + fn*16 + lr;
                float v = acc[fm][fn][q] + biasv[Lz*768 + col];
                int b = row >> 8, tl = row & 255;
                int group = b >> 4, s = b & 15;
                int wv  = (col & 255) >> 6;
                int sub = (col >> 4) & 3;
                int g   = col >> 8;
                int lane2 = ((s >> 2) << 4) | (col & 15);
                int qq  = s & 3;
                size_t off = (((size_t)(group*CH + tl)*4 + wv)*64 + lane2)*48
                           + (size_t)(g*4 + sub)*4 + qq;
                proj[off] = __float2half(v);
            }
}

// ---------------- MFMA recurrence ---------------------------------------------------------
// 8 blocks = 2 layers x 4 groups of 16 samples. 256 thr (4 waves), 1 wave/SIMD (512 VGPR).
// Wave w owns cols [64w, 64w+64): 4 n-tiles each of r/z/h~. Weights = 96 B-frags resident.
__global__ __launch_bounds__(256)
__attribute__((amdgpu_waves_per_eu(1, 1)))
void rec_mfma(const __half* __restrict__ wfrag,
              const __half* __restrict__ proj0, const __half* __restrict__ proj1,
              __half* __restrict__ h0chunk, float* __restrict__ hstate,
              const float* __restrict__ Wfc, const float* __restrict__ bfc,
              float* __restrict__ out, int c0, int c1)
{
    __shared__ __align__(16) _Float16 s_h[4096];   // [16 samples][256] swizzled
    __shared__ __align__(16) _Float16 s_rh[4096];
    __shared__ float s_head[4096];                 // [16][256] f32 final h

    const int L   = blockIdx.x >> 2;
    const int grp = blockIdx.x & 3;
    const int c   = L ? c1 : c0;
    if (c < 0 || c >= NCH) return;

    const int tid = threadIdx.x;
    const int w   = tid >> 6;
    const int l   = tid & 63;
    const int lr  = l & 15;
    const int lk  = l >> 4;

    // 96 resident B-fragments: wf[t][kt], t = g*4+sub
    f16x8 wf[12][8];
    {
        const __half* wb = wfrag + ((size_t)(L*4 + w)*96)*512 + (size_t)l*8;
#pragma unroll
        for (int t = 0; t < 12; ++t)
#pragma unroll
            for (int kt = 0; kt < 8; ++kt)
                wf[t][kt] = *(const f16x8*)(wb + (size_t)(t*8 + kt)*512);
    }

    // persistent h (D-layout): hreg[sub][q] holds (s = lk*4+q, col = 64w + sub*16 + lr)
    float hreg[4][4];
#pragma unroll
    for (int sub = 0; sub < 4; ++sub)
#pragma unroll
        for (int q = 0; q < 4; ++q) {
            int s = lk*4 + q, col = w*64 + sub*16 + lr;
            hreg[sub][q] = (c == 0) ? 0.f
                : hstate[((size_t)(L*NB + grp*16 + s))*HID + col];
            int addr = s*512 + ((col*2) ^ ((s & 7) << 4));
            *(_Float16*)((char*)s_h + addr) = (_Float16)hreg[sub][q];
        }
    __syncthreads();

    const __half* prow = (L ? proj1 : proj0)
        + ((size_t)grp*CH*4 + w)*3072 + (size_t)l*48;

#pragma unroll 1
    for (int tl = 0; tl < CH; ++tl) {
        const __half* pp = prow + (size_t)tl*12288;
        uint4 pjr0 = *(const uint4*)(pp);        // r: sub 0-1
        uint4 pjr1 = *(const uint4*)(pp + 8);    // r: sub 2-3
        uint4 pjz0 = *(const uint4*)(pp + 16);   // z: sub 0-1
        uint4 pjz1 = *(const uint4*)(pp + 24);   // z: sub 2-3

        // A-fragments of h (s = lr)
        f16x8 ha[8];
#pragma unroll
        for (int kt = 0; kt < 8; ++kt) {
            int addr = lr*512 + ((kt*64 + lk*16) ^ ((lr & 7) << 4));
            ha[kt] = *(const f16x8*)((const char*)s_h + addr);
        }

        uint32_t zpk[4][2];
        // phase A: r,z — two groups of 4 interleaved MFMA chains
#pragma unroll
        for (int g2 = 0; g2 < 2; ++g2) {
            const int s0 = g2*2, s1 = g2*2 + 1;
            f32x4 ar0 = {}, az0 = {}, ar1 = {}, az1 = {};
#pragma unroll
            for (int kt = 0; kt < 8; ++kt) {
                ar0 = mfma16(ha[kt], wf[s0][kt],     ar0);
                az0 = mfma16(ha[kt], wf[4 + s0][kt], az0);
                ar1 = mfma16(ha[kt], wf[s1][kt],     ar1);
                az1 = mfma16(ha[kt], wf[4 + s1][kt], az1);
            }
#pragma unroll
            for (int h2i = 0; h2i < 2; ++h2i) {
                const int sub = g2*2 + h2i;
                f32x4 ar = h2i ? ar1 : ar0;
                f32x4 az = h2i ? az1 : az0;
                uint4 vr = (sub < 2) ? pjr0 : pjr1;
                uint4 vz = (sub < 2) ? pjz0 : pjz1;
                float zq[4];
#pragma unroll
                for (int q = 0; q < 4; ++q) {
                    int s = lk*4 + q, col = w*64 + sub*16 + lr;
                    float r = sigm_(ar[q] + f16x(vr, (sub & 1)*4 + q));
                    zq[q]   = sigm_(az[q] + f16x(vz, (sub & 1)*4 + q));
                    float rh = r * hreg[sub][q];
                    int addr = s*512 + ((col*2) ^ ((s & 7) << 4));
                    *(_Float16*)((char*)s_rh + addr) = (_Float16)rh;
                }
                h2_t z01; z01[0] = (_Float16)zq[0]; z01[1] = (_Float16)zq[1];
                h2_t z23; z23[0] = (_Float16)zq[2]; z23[1] = (_Float16)zq[3];
                zpk[sub][0] = __builtin_bit_cast(uint32_t, z01);
                zpk[sub][1] = __builtin_bit_cast(uint32_t, z23);
            }
        }

        uint4 pjh0 = *(const uint4*)(pp + 32);   // h~: sub 0-1
        uint4 pjh1 = *(const uint4*)(pp + 40);   // h~: sub 2-3
        sync_lds();

        // phase B: candidate over r*h
        f16x8 ra[8];
#pragma unroll
        for (int kt = 0; kt < 8; ++kt) {
            int addr = lr*512 + ((kt*64 + lk*16) ^ ((lr & 7) << 4));
            ra[kt] = *(const f16x8*)((const char*)s_rh + addr);
        }
        f32x4 ah[4] = {};
#pragma unroll
        for (int kt = 0; kt < 8; ++kt)
#pragma unroll
            for (int sub = 0; sub < 4; ++sub)
                ah[sub] = mfma16(ra[kt], wf[8 + sub][kt], ah[sub]);

#pragma unroll
        for (int sub = 0; sub < 4; ++sub) {
            uint4 vh = (sub < 2) ? pjh0 : pjh1;
#pragma unroll
            for (int q = 0; q < 4; ++q) {
                int s = lk*4 + q, col = w*64 + sub*16 + lr;
                float th = tanh_(ah[sub][q] + f16x(vh, (sub & 1)*4 + q));
                h2_t zz = bc_h2(zpk[sub][q >> 1]);
                float z = (float)zz[q & 1];
                float h = hreg[sub][q];
                h += z*(th - h);
                hreg[sub][q] = h;
                int addr = s*512 + ((col*2) ^ ((s & 7) << 4));
                *(_Float16*)((char*)s_h + addr) = (_Float16)h;
                if (tl == CH-1) {
                    s_head[s*256 + col] = h;
                    hstate[((size_t)(L*NB + grp*16 + s))*HID + col] = h;
                }
            }
        }
        sync_lds();

        // h0chunk: coalesced staging copy of this step's s_h (L0 only)
        if (L == 0) {
            int idx2 = tid << 1;
            int s2 = idx2 >> 5;          // [0,16)
            int m  = idx2 & 31;          // even
            const char* srcb = (const char*)s_h + s2*512;
            uint4 v0 = *(const uint4*)(srcb + ((m*16)       ^ ((s2 & 7) << 4)));
            uint4 v1 = *(const uint4*)(srcb + (((m + 1)*16) ^ ((s2 & 7) << 4)));
            uint4* dst = (uint4*)(h0chunk + ((size_t)(grp*16 + s2)*CH + tl)*HID) + m;
            dst[0] = v0;
            dst[1] = v1;
        }
    }

    // classification head (L1, last chunk) — from block-local s_head
    if (L == 1 && c == NCH-1) {
        __syncthreads();
        if (tid < 64) {
            int s = tid >> 2, part = tid & 3;
            const float* hrow = s_head + s*256 + part*64;
            float p0 = 0.f, p1 = 0.f;
#pragma unroll 4
            for (int i = 0; i < 64; ++i) {
                float hv = hrow[i];
                p0 += hv * Wfc[(part*64 + i)*2 + 0];
                p1 += hv * Wfc[(part*64 + i)*2 + 1];
            }
            p0 += __shfl_xor(p0, 1); p0 += __shfl_xor(p0, 2);
            p1 += __shfl_xor(p1, 1); p1 += __shfl_xor(p1, 2);
            if (part == 0) {
                out[(grp*16 + s)*2 + 0] = p0 + bfc[0];
                out[(grp*16 + s)*2 + 1] = p1 + bfc[1];
            }
        }
    }
}

// ---------------- host ----------------
extern "C" void kernel_launch(void* const* d_in, const int* in_sizes, int n_in,
                              void* d_out, int out_size, void* d_ws, size_t ws_size,
                              hipStream_t stream) {
    const int*   tokens = (const int*)  d_in[0];
    const float* emb    = (const float*)d_in[1];
    const float* Wr     = (const float*)d_in[2];
    const float* br     = (const float*)d_in[3];
    const float* Wz     = (const float*)d_in[4];
    const float* bz     = (const float*)d_in[5];
    const float* Wh     = (const float*)d_in[6];
    const float* bh     = (const float*)d_in[7];
    const float* Wfc    = (const float*)d_in[8];
    const float* bfc    = (const float*)d_in[9];
    float* out = (float*)d_out;

    char* ws = (char*)d_ws;
    __half*   wfrag  = (__half*)(ws + 0);                 //    786,432 B
    __half*   wxt    = (__half*)(ws + (1u<<20));          //    786,432 B
    __half*   embf16 = (__half*)(ws + (2u<<20));          // 16,384,000 B
    __half*   proj0  = (__half*)(ws + 18874368u);         // 25,165,824 B
    __half*   proj1  = (__half*)(ws + 44040192u);         // 25,165,824 B
    __half*   h0chunk= (__half*)(ws + 69206016u);         //  8,388,608 B
    float*    hstate = (float*)(ws + 77594624u);          //    131,072 B
    float*    biasv  = (float*)(ws + 77725696u);          //      6,144 B

    prep_kernel<<<2048, 256, 0, stream>>>(Wr, Wz, Wh, emb, br, bz, bh,
                                          wfrag, wxt, embf16, biasv);

    dim3 ggrid(128, 12, 2);
    for (int c = 0; c <= NCH; ++c) {
        int cc0 = (c < NCH) ? c : -1;
        int cc1 = c - 1;
        gemm_proj<<<ggrid, 256, 0, stream>>>(tokens, embf16, h0chunk, wxt, biasv,
                                             proj0, proj1, cc0, cc1);
        rec_mfma<<<8, 256, 0, stream>>>(wfrag, proj0, proj1, h0chunk, hstate,
                                        Wfc, bfc, out, cc0, cc1);
    }
}